// Round 6
// baseline (299.750 us; speedup 1.0000x reference)
//
#include <hip/hip_runtime.h>
#include <math.h>

// Problem constants (B,N,F_IN,HID,OUT,H,D) = (32,512,256,512,512,4,128)
#define BATCH 32
#define NNODE 512
#define FIN   256
#define HIDC  512
#define OUTC  512
#define NHEAD 4
#define HDIM  128
#define EPSV  1e-5f
#define ALPHA_LR 0.2f

typedef _Float16 half8 __attribute__((ext_vector_type(8)));
typedef _Float16 half4v __attribute__((ext_vector_type(4)));
typedef float floatx4 __attribute__((ext_vector_type(4)));

#define GLOBAL_TO_LDS16(g, l)                                                  \
  __builtin_amdgcn_global_load_lds(                                            \
      (const __attribute__((address_space(1))) void*)(g),                      \
      (__attribute__((address_space(3))) void*)(l), 16, 0, 0)

// ---------------------------------------------------------------------------
// Generic 128x128 split-fp16 MFMA GEMM core (unchanged).
// ---------------------------------------------------------------------------
__device__ __forceinline__ void split_gemm_acc(
    const _Float16* __restrict__ Ah, const _Float16* __restrict__ Al, int lda,
    const _Float16* __restrict__ Bh, const _Float16* __restrict__ Bl, int ldb,
    int K, int rowBase, int colBase,
    _Float16* sAh, _Float16* sAl, _Float16* sBh, _Float16* sBl,
    floatx4 acc[4][4], int tid) {
  const int lane = tid & 63, wave = tid >> 6;
  const int wr = (wave >> 1) * 64, wc = (wave & 1) * 64;
  const int fr = lane & 15, q = lane >> 4;
  const int r = tid >> 2, ko = (tid & 3) * 8;
  for (int k0 = 0; k0 < K; k0 += 32) {
    GLOBAL_TO_LDS16(&Ah[(size_t)(rowBase + r) * lda + k0 + ko], &sAh[tid * 8]);
    GLOBAL_TO_LDS16(&Ah[(size_t)(rowBase + r + 64) * lda + k0 + ko], &sAh[2048 + tid * 8]);
    GLOBAL_TO_LDS16(&Al[(size_t)(rowBase + r) * lda + k0 + ko], &sAl[tid * 8]);
    GLOBAL_TO_LDS16(&Al[(size_t)(rowBase + r + 64) * lda + k0 + ko], &sAl[2048 + tid * 8]);
    GLOBAL_TO_LDS16(&Bh[(size_t)(colBase + r) * ldb + k0 + ko], &sBh[tid * 8]);
    GLOBAL_TO_LDS16(&Bh[(size_t)(colBase + r + 64) * ldb + k0 + ko], &sBh[2048 + tid * 8]);
    GLOBAL_TO_LDS16(&Bl[(size_t)(colBase + r) * ldb + k0 + ko], &sBl[tid * 8]);
    GLOBAL_TO_LDS16(&Bl[(size_t)(colBase + r + 64) * ldb + k0 + ko], &sBl[2048 + tid * 8]);
    __syncthreads();
    half8 ah[4], al4[4], bh[4], bl4[4];
#pragma unroll
    for (int i = 0; i < 4; ++i) {
      ah[i]  = *(const half8*)&sAh[(wr + i * 16 + fr) * 32 + q * 8];
      al4[i] = *(const half8*)&sAl[(wr + i * 16 + fr) * 32 + q * 8];
    }
#pragma unroll
    for (int j = 0; j < 4; ++j) {
      bh[j]  = *(const half8*)&sBh[(wc + j * 16 + fr) * 32 + q * 8];
      bl4[j] = *(const half8*)&sBl[(wc + j * 16 + fr) * 32 + q * 8];
    }
#pragma unroll
    for (int i = 0; i < 4; ++i)
#pragma unroll
      for (int j = 0; j < 4; ++j) {
        acc[i][j] = __builtin_amdgcn_mfma_f32_16x16x32_f16(al4[i], bh[j], acc[i][j], 0, 0, 0);
        acc[i][j] = __builtin_amdgcn_mfma_f32_16x16x32_f16(ah[i], bl4[j], acc[i][j], 0, 0, 0);
        acc[i][j] = __builtin_amdgcn_mfma_f32_16x16x32_f16(ah[i], bh[j], acc[i][j], 0, 0, 0);
      }
    __syncthreads();
  }
}

// ---------------------------------------------------------------------------
// Prep (unchanged): splits + conv weight transform + OP halo zero.
// ---------------------------------------------------------------------------
__global__ __launch_bounds__(256) void k_prep(
    const float* __restrict__ adj, const float* __restrict__ gcw,
    const float* __restrict__ gatw, const float* __restrict__ cw,
    _Float16* __restrict__ ADJh, _Float16* __restrict__ ADJl,
    _Float16* __restrict__ GWh, _Float16* __restrict__ GWl,
    _Float16* __restrict__ GAh, _Float16* __restrict__ GAl,
    _Float16* __restrict__ WT, _Float16* __restrict__ OP) {
  const int i = blockIdx.x * 256 + threadIdx.x;
  if (i < 262144) {
    float v = adj[i];
    _Float16 h = (_Float16)v;
    ADJh[i] = h; ADJl[i] = (_Float16)(v - (float)h);
  } else if (i < 393216) {
    int j = i - 262144;
    int n = j >> 8, k = j & 255;
    float v = gcw[(size_t)k * HIDC + n];
    _Float16 h = (_Float16)v;
    GWh[j] = h; GWl[j] = (_Float16)(v - (float)h);
  } else if (i < 655360) {
    int j = i - 393216;
    float v = gatw[j];
    _Float16 h = (_Float16)v;
    GAh[j] = h; GAl[j] = (_Float16)(v - (float)h);
  } else if (i < 1441792) {
    int j = i - 655360;
    int n = j / 1536, kk = j - n * 1536;
    int tap = kk >> 9, ci = kk & 511;
    WT[j] = (_Float16)cw[(size_t)n * 1536 + ci * 3 + tap];
  } else if (i < 1474560) {
    int j = i - 1441792;
    int b = j >> 10, rs = (j >> 9) & 1, c = j & 511;
    OP[((size_t)b * 514 + rs * 513) * OUTC + c] = (_Float16)0.f;
  }
}

// x [16384,256] fp32 -> hi/lo fp16
__global__ __launch_bounds__(256) void k_xsplit(const float* __restrict__ X,
                                                _Float16* __restrict__ Xh,
                                                _Float16* __restrict__ Xl) {
  const int i = (blockIdx.x * 256 + threadIdx.x) * 4;
  float4 v = *(const float4*)&X[i];
  half4v h, l;
  h[0] = (_Float16)v.x; l[0] = (_Float16)(v.x - (float)h[0]);
  h[1] = (_Float16)v.y; l[1] = (_Float16)(v.y - (float)h[1]);
  h[2] = (_Float16)v.z; l[2] = (_Float16)(v.z - (float)h[2]);
  h[3] = (_Float16)v.w; l[3] = (_Float16)(v.w - (float)h[3]);
  *(half4v*)&Xh[i] = h;
  *(half4v*)&Xl[i] = l;
}

// ---------------------------------------------------------------------------
// support^T = gc_w^T @ x^T (unchanged)
// ---------------------------------------------------------------------------
__global__ __launch_bounds__(256) void k_support_t(
    const _Float16* __restrict__ GWh, const _Float16* __restrict__ GWl,
    const _Float16* __restrict__ Xh, const _Float16* __restrict__ Xl,
    _Float16* __restrict__ STh, _Float16* __restrict__ STl) {
  __shared__ _Float16 sm[4][4096];
  const int tid = threadIdx.x;
  const int rowBase = blockIdx.y * 128, colBase = blockIdx.x * 128;
  floatx4 acc[4][4] = {};
  split_gemm_acc(GWh, GWl, FIN, Xh, Xl, FIN, FIN, rowBase, colBase,
                 sm[0], sm[1], sm[2], sm[3], acc, tid);
  const int lane = tid & 63, wave = tid >> 6;
  const int wr = (wave >> 1) * 64, wc = (wave & 1) * 64;
  const int fr = lane & 15, q = lane >> 4;
#pragma unroll
  for (int i = 0; i < 4; ++i) {
    const int ch0 = rowBase + wr + i * 16 + q * 4;
#pragma unroll
    for (int rg = 0; rg < 4; ++rg) {
      size_t base = (size_t)(ch0 + rg) * 16384 + colBase + wc + fr;
#pragma unroll
      for (int j = 0; j < 4; ++j) {
        float v = acc[i][j][rg];
        _Float16 h = (_Float16)v;
        STh[base + j * 16] = h;
        STl[base + j * 16] = (_Float16)(v - (float)h);
      }
    }
  }
}

// ---------------------------------------------------------------------------
// g = relu(bn1(adj @ support_b + gc_b)) (unchanged)
// ---------------------------------------------------------------------------
__global__ __launch_bounds__(256) void k_gcn(
    const _Float16* __restrict__ ADJh, const _Float16* __restrict__ ADJl,
    const _Float16* __restrict__ STh, const _Float16* __restrict__ STl,
    const float* __restrict__ gcb, const float* __restrict__ g1,
    const float* __restrict__ b1, const float* __restrict__ m1,
    const float* __restrict__ v1,
    _Float16* __restrict__ Gh, _Float16* __restrict__ Gl) {
  __shared__ _Float16 sm[4][4096];
  const int tid = threadIdx.x;
  const int rowBase = blockIdx.y * 128, colBase = blockIdx.x * 128;
  const int b = blockIdx.z;
  floatx4 acc[4][4] = {};
  split_gemm_acc(ADJh, ADJl, NNODE, STh + (size_t)b * NNODE, STl + (size_t)b * NNODE,
                 16384, NNODE, rowBase, colBase, sm[0], sm[1], sm[2], sm[3], acc, tid);
  const int lane = tid & 63, wave = tid >> 6;
  const int wr = (wave >> 1) * 64, wc = (wave & 1) * 64;
  const int fr = lane & 15, q = lane >> 4;
  float sc[4], of[4];
#pragma unroll
  for (int j = 0; j < 4; ++j) {
    int c = colBase + wc + j * 16 + fr;
    float s = g1[c] * rsqrtf(v1[c] + EPSV);
    sc[j] = s;
    of[j] = (gcb[c] - m1[c]) * s + b1[c];
  }
#pragma unroll
  for (int i = 0; i < 4; ++i) {
    const int n0 = rowBase + wr + i * 16 + q * 4;
#pragma unroll
    for (int rg = 0; rg < 4; ++rg) {
      size_t base = ((size_t)b * NNODE + n0 + rg) * HIDC + colBase + wc + fr;
#pragma unroll
      for (int j = 0; j < 4; ++j) {
        float v = fmaxf(fmaf(acc[i][j][rg], sc[j], of[j]), 0.0f);
        _Float16 h = (_Float16)v;
        Gh[base + j * 16] = h;
        Gl[base + j * 16] = (_Float16)(v - (float)h);
      }
    }
  }
}

// ---------------------------------------------------------------------------
// hh = g @ gat_w^T (unchanged)
// ---------------------------------------------------------------------------
__global__ __launch_bounds__(256) void k_hh(
    const _Float16* __restrict__ Gh, const _Float16* __restrict__ Gl,
    const _Float16* __restrict__ GAh, const _Float16* __restrict__ GAl,
    _Float16* __restrict__ HHh, _Float16* __restrict__ HHl) {
  __shared__ _Float16 sm[4][4096];
  const int tid = threadIdx.x;
  const int rowBase = blockIdx.y * 128, colBase = blockIdx.x * 128;
  floatx4 acc[4][4] = {};
  split_gemm_acc(Gh, Gl, HIDC, GAh, GAl, HIDC, HIDC, rowBase, colBase,
                 sm[0], sm[1], sm[2], sm[3], acc, tid);
  const int lane = tid & 63, wave = tid >> 6;
  const int wr = (wave >> 1) * 64, wc = (wave & 1) * 64;
  const int fr = lane & 15, q = lane >> 4;
#pragma unroll
  for (int i = 0; i < 4; ++i) {
    const int r0 = rowBase + wr + i * 16 + q * 4;
#pragma unroll
    for (int rg = 0; rg < 4; ++rg) {
      size_t base = (size_t)(r0 + rg) * OUTC + colBase + wc + fr;
#pragma unroll
      for (int j = 0; j < 4; ++j) {
        float v = acc[i][j][rg];
        _Float16 h = (_Float16)v;
        HHh[base + j * 16] = h;
        HHl[base + j * 16] = (_Float16)(v - (float)h);
      }
    }
  }
}

// ---------------------------------------------------------------------------
// k_vt: HHT[(bb*4+h)*128 + d][node] = HHh[bb*512+node][h*128+d]
// One block per (bb,h,node-tile 128). LDS-tiled for coalesced read+write.
// ---------------------------------------------------------------------------
__global__ __launch_bounds__(256) void k_vt(const _Float16* __restrict__ HHh,
                                            _Float16* __restrict__ HHT) {
  __shared__ _Float16 sT[128 * 132];
  const int bt = blockIdx.x;           // 0..511
  const int nt = bt & 3, g = bt >> 2;  // g = bb*4+h
  const int bb = g >> 2, h = g & 3;
  const int tid = threadIdx.x;
  const int rr = tid >> 4, cc = (tid & 15) * 8;
#pragma unroll
  for (int it = 0; it < 8; ++it) {
    int node = rr + it * 16;
    half8 v = *(const half8*)&HHh[((size_t)bb * 512 + nt * 128 + node) * 512 + h * 128 + cc];
#pragma unroll
    for (int e = 0; e < 8; ++e) sT[(cc + e) * 132 + node] = v[e];
  }
  __syncthreads();
#pragma unroll
  for (int it = 0; it < 8; ++it) {
    int d = rr + it * 16;
    half8 v;
#pragma unroll
    for (int e = 0; e < 8; ++e) v[e] = sT[d * 132 + cc + e];
    *(half8*)&HHT[((size_t)g * 128 + d) * 512 + nt * 128 + cc] = v;
  }
}

// ---------------------------------------------------------------------------
// Fused flash attention, 64-q blocks, grid 1024, XCD-grouped.
// Q frags in regs (loaded once). Per kt: split-fp16 QK^T (K staged BK=32),
// online softmax in regs, then per-ks(32 keys): P chunk -> sP (stride 44,
// conflict-free), V chunk async from HHT, plain fp16 PV.
// LDS = 29.5 KB; launch_bounds(256,3) -> 3 blocks/CU.
// ---------------------------------------------------------------------------
__global__ __launch_bounds__(256, 3) void k_attn(
    const _Float16* __restrict__ HHh, const _Float16* __restrict__ HHl,
    const _Float16* __restrict__ HHT, _Float16* __restrict__ OP) {
  __shared__ _Float16 sKh[128 * 32], sKl[128 * 32];  // [key][32 d]
  __shared__ _Float16 sV[128 * 32];                   // [d][32 keys]
  __shared__ _Float16 sP[64 * 44];                    // [qrow][32 keys pad->44]
  const int tid = threadIdx.x;
  const int lane = tid & 63, wave = tid >> 6;
  const int fr = lane & 15, q = lane >> 4;
  // XCD grouping: all 8 q-slots of one (bb,h) share id%8.
  const int id = blockIdx.x;
  const int slot = id >> 3;
  const int g = (id & 7) + 8 * (slot >> 3);   // 0..127
  const int qBase = (slot & 7) * 64;
  const int bb = g >> 2, h = g & 3;
  const int w16 = wave * 16;
  const _Float16* Qh = HHh + (size_t)bb * NNODE * OUTC + h * HDIM;
  const _Float16* Ql = HHl + (size_t)bb * NNODE * OUTC + h * HDIM;
  const _Float16* VT = HHT + (size_t)g * HDIM * NNODE;  // [128 d][512 nodes]
  const int r = tid >> 2, ko = (tid & 3) * 8;

  // Q fragments in registers (A layout: m=fr, k=k0*32+q*8+j), loaded once.
  half8 qh[4], ql[4];
#pragma unroll
  for (int k0 = 0; k0 < 4; ++k0) {
    const size_t off = (size_t)(qBase + w16 + fr) * OUTC + k0 * 32 + q * 8;
    qh[k0] = *(const half8*)&Qh[off];
    ql[k0] = *(const half8*)&Ql[off];
  }

  floatx4 oacc[8] = {};
  float m_i[4], l_i[4];
#pragma unroll
  for (int rg = 0; rg < 4; ++rg) { m_i[rg] = -1e30f; l_i[rg] = 0.f; }

  for (int kt = 0; kt < 4; ++kt) {
    const int ktb = kt * 128;
    // ---- S = Q @ K^T (split-fp16), 128 keys ----
    floatx4 sacc[8] = {};
#pragma unroll
    for (int k0 = 0; k0 < 4; ++k0) {
      GLOBAL_TO_LDS16(&Qh[(size_t)(ktb + r) * OUTC + k0 * 32 + ko], &sKh[tid * 8]);
      GLOBAL_TO_LDS16(&Qh[(size_t)(ktb + r + 64) * OUTC + k0 * 32 + ko], &sKh[2048 + tid * 8]);
      GLOBAL_TO_LDS16(&Ql[(size_t)(ktb + r) * OUTC + k0 * 32 + ko], &sKl[tid * 8]);
      GLOBAL_TO_LDS16(&Ql[(size_t)(ktb + r + 64) * OUTC + k0 * 32 + ko], &sKl[2048 + tid * 8]);
      __syncthreads();
#pragma unroll
      for (int j = 0; j < 8; ++j) {
        half8 bh = *(const half8*)&sKh[(j * 16 + fr) * 32 + q * 8];
        half8 bl = *(const half8*)&sKl[(j * 16 + fr) * 32 + q * 8];
        sacc[j] = __builtin_amdgcn_mfma_f32_16x16x32_f16(ql[k0], bh, sacc[j], 0, 0, 0);
        sacc[j] = __builtin_amdgcn_mfma_f32_16x16x32_f16(qh[k0], bl, sacc[j], 0, 0, 0);
        sacc[j] = __builtin_amdgcn_mfma_f32_16x16x32_f16(qh[k0], bh, sacc[j], 0, 0, 0);
      }
      __syncthreads();
    }
    // ---- LeakyReLU + online softmax (rows = q*4+rg, cols = j*16+fr) ----
#pragma unroll
    for (int j = 0; j < 8; ++j)
#pragma unroll
      for (int rg = 0; rg < 4; ++rg) {
        float v = sacc[j][rg];
        sacc[j][rg] = v > 0.f ? v : ALPHA_LR * v;
      }
#pragma unroll
    for (int rg = 0; rg < 4; ++rg) {
      float mx = sacc[0][rg];
#pragma unroll
      for (int j = 1; j < 8; ++j) mx = fmaxf(mx, sacc[j][rg]);
      mx = fmaxf(mx, __shfl_xor(mx, 1));
      mx = fmaxf(mx, __shfl_xor(mx, 2));
      mx = fmaxf(mx, __shfl_xor(mx, 4));
      mx = fmaxf(mx, __shfl_xor(mx, 8));
      float mnew = fmaxf(m_i[rg], mx);
      float alpha = __expf(m_i[rg] - mnew);
      m_i[rg] = mnew;
      float sum = 0.f;
#pragma unroll
      for (int j = 0; j < 8; ++j) {
        float p = __expf(sacc[j][rg] - mnew);
        sacc[j][rg] = p;           // P now lives in sacc
        sum += p;
      }
      sum += __shfl_xor(sum, 1);
      sum += __shfl_xor(sum, 2);
      sum += __shfl_xor(sum, 4);
      sum += __shfl_xor(sum, 8);
      l_i[rg] = l_i[rg] * alpha + sum;
#pragma unroll
      for (int j = 0; j < 8; ++j) oacc[j][rg] *= alpha;
    }
    // ---- O += P @ V per 32-key chunk (plain fp16, V from HHT async) ----
#pragma unroll
    for (int ks = 0; ks < 4; ++ks) {
#pragma unroll
      for (int jj = 0; jj < 2; ++jj)
#pragma unroll
        for (int rg = 0; rg < 4; ++rg)
          sP[(w16 + q * 4 + rg) * 44 + jj * 16 + fr] = (_Float16)sacc[2 * ks + jj][rg];
      GLOBAL_TO_LDS16(&VT[(size_t)r * NNODE + ktb + ks * 32 + ko], &sV[tid * 8]);
      GLOBAL_TO_LDS16(&VT[(size_t)(r + 64) * NNODE + ktb + ks * 32 + ko], &sV[2048 + tid * 8]);
      __syncthreads();
      half8 pa = *(const half8*)&sP[(w16 + fr) * 44 + q * 8];
#pragma unroll
      for (int j = 0; j < 8; ++j) {
        half8 bv = *(const half8*)&sV[(j * 16 + fr) * 32 + q * 8];
        oacc[j] = __builtin_amdgcn_mfma_f32_16x16x32_f16(pa, bv, oacc[j], 0, 0, 0);
      }
      __syncthreads();
    }
  }
  // ---- normalize + write into padded conv input ----
#pragma unroll
  for (int rg = 0; rg < 4; ++rg) {
    const float inv = 1.0f / l_i[rg];
    const int node = qBase + w16 + q * 4 + rg;
    size_t base = ((size_t)bb * 514 + 1 + node) * OUTC + h * HDIM + fr;
#pragma unroll
    for (int j = 0; j < 8; ++j)
      OP[base + j * 16] = (_Float16)(oacc[j][rg] * inv);
  }
}

// ---------------------------------------------------------------------------
// y = relu(bn2(conv1d(o)+conv_b)) via fp16 MFMA GEMM, XCD-swizzled (unchanged)
// ---------------------------------------------------------------------------
__global__ __launch_bounds__(256) void k_conv_mfma(
    const _Float16* __restrict__ OP, const _Float16* __restrict__ WT,
    const float* __restrict__ cb, const float* __restrict__ g2,
    const float* __restrict__ b2, const float* __restrict__ m2,
    const float* __restrict__ v2, float* __restrict__ Y) {
  __shared__ _Float16 At[128 * 32];
  __shared__ _Float16 Bt[128 * 32];
  const int tid = threadIdx.x;
  const int lane = tid & 63, wave = tid >> 6;
  const int wr = (wave >> 1) * 64, wc = (wave & 1) * 64;
  const int id = blockIdx.y * 4 + blockIdx.x;
  const int jj = id >> 3;
  const int rowBase = ((id & 7) * 16 + (jj >> 2)) * 128;
  const int colBase = (jj & 3) * 128;
  const int b = rowBase >> 9;
  const int n0 = rowBase & 511;
  const int r = tid >> 2;
  const int ko = (tid & 3) * 8;
  floatx4 acc[4][4] = {};
  for (int k0 = 0; k0 < 3 * OUTC; k0 += 32) {
    const int tap = k0 >> 9;
    const int cib = k0 & 511;
    const size_t abase = ((size_t)b * 514 + n0 + tap) * OUTC + cib + ko;
    GLOBAL_TO_LDS16(&OP[abase + (size_t)r * OUTC],        &At[tid * 8]);
    GLOBAL_TO_LDS16(&OP[abase + (size_t)(r + 64) * OUTC], &At[2048 + tid * 8]);
    GLOBAL_TO_LDS16(&WT[(size_t)(colBase + r) * 1536 + k0 + ko],      &Bt[tid * 8]);
    GLOBAL_TO_LDS16(&WT[(size_t)(colBase + r + 64) * 1536 + k0 + ko], &Bt[2048 + tid * 8]);
    __syncthreads();
    const int fr = lane & 15, q = lane >> 4;
    half8 af[4], bf[4];
#pragma unroll
    for (int i = 0; i < 4; ++i)
      af[i] = *(const half8*)&At[(wr + i * 16 + fr) * 32 + q * 8];
#pragma unroll
    for (int j = 0; j < 4; ++j)
      bf[j] = *(const half8*)&Bt[(wc + j * 16 + fr) * 32 + q * 8];
#pragma unroll
    for (int i = 0; i < 4; ++i)
#pragma unroll
      for (int j = 0; j < 4; ++j)
        acc[i][j] = __builtin_amdgcn_mfma_f32_16x16x32_f16(af[i], bf[j], acc[i][j], 0, 0, 0);
    __syncthreads();
  }
  const int fr = lane & 15, q = lane >> 4;
  float sc[4], of[4];
#pragma unroll
  for (int j = 0; j < 4; ++j) {
    int c = colBase + wc + j * 16 + fr;
    float s = g2[c] * rsqrtf(v2[c] + EPSV);
    sc[j] = s;
    of[j] = (cb[c] - m2[c]) * s + b2[c];
  }
#pragma unroll
  for (int i = 0; i < 4; ++i) {
    const int R0r = rowBase + wr + i * 16 + q * 4;
#pragma unroll
    for (int rg = 0; rg < 4; ++rg) {
      float* dst = &Y[(size_t)(R0r + rg) * OUTC + colBase + wc + fr];
#pragma unroll
      for (int j = 0; j < 4; ++j)
        dst[j * 16] = fmaxf(fmaf(acc[i][j][rg], sc[j], of[j]), 0.0f);
    }
  }
}

// ---------------------------------------------------------------------------
extern "C" void kernel_launch(void* const* d_in, const int* in_sizes, int n_in,
                              void* d_out, int out_size, void* d_ws, size_t ws_size,
                              hipStream_t stream) {
  const float* x     = (const float*)d_in[0];
  const float* adj   = (const float*)d_in[1];
  const float* gc_w  = (const float*)d_in[2];
  const float* gc_b  = (const float*)d_in[3];
  const float* bn1_g = (const float*)d_in[4];
  const float* bn1_b = (const float*)d_in[5];
  const float* bn1_m = (const float*)d_in[6];
  const float* bn1_v = (const float*)d_in[7];
  const float* gat_w = (const float*)d_in[8];
  const float* conv_w= (const float*)d_in[9];
  const float* conv_b= (const float*)d_in[10];
  const float* bn2_g = (const float*)d_in[11];
  const float* bn2_b = (const float*)d_in[12];
  const float* bn2_m = (const float*)d_in[13];
  const float* bn2_v = (const float*)d_in[14];
  float* out = (float*)d_out;

  // Lifetime-packed workspace (96 MiB):
  //  [0,16M):      st_hi -> hh_hi        [16M,32M): st_lo -> hh_lo
  //  [32M,64M):    x_hi+x_lo -> g_hi(@32M)+g_lo(@48M) -> HHT(@32M, 16.8M)
  //  [64M,80.07M): OP fp16 padded conv input
  //  [80.07M..):   WT, adj/gcwt/gatw hi/lo splits
  char* ws = (char*)d_ws;
  _Float16* STh = (_Float16*)(ws + 0);
  _Float16* STl = (_Float16*)(ws + 16777216);
  _Float16* HHh = (_Float16*)(ws + 0);
  _Float16* HHl = (_Float16*)(ws + 16777216);
  _Float16* Xh  = (_Float16*)(ws + 33554432);
  _Float16* Xl  = (_Float16*)(ws + 41943040);
  _Float16* Gh  = (_Float16*)(ws + 33554432);
  _Float16* Gl  = (_Float16*)(ws + 50331648);
  _Float16* HHT = (_Float16*)(ws + 33554432);
  _Float16* OP  = (_Float16*)(ws + 67108864);
  _Float16* WT  = (_Float16*)(ws + 83951616);
  _Float16* ADJh= (_Float16*)(ws + 85524480);
  _Float16* ADJl= (_Float16*)(ws + 86048768);
  _Float16* GWh = (_Float16*)(ws + 86573056);
  _Float16* GWl = (_Float16*)(ws + 86835200);
  _Float16* GAh = (_Float16*)(ws + 87097344);
  _Float16* GAl = (_Float16*)(ws + 87621632);

  k_prep<<<5760, 256, 0, stream>>>(adj, gc_w, gat_w, conv_w,
                                   ADJh, ADJl, GWh, GWl, GAh, GAl, WT, OP);
  k_xsplit<<<4096, 256, 0, stream>>>(x, Xh, Xl);
  k_support_t<<<dim3(128, 4), 256, 0, stream>>>(GWh, GWl, Xh, Xl, STh, STl);
  k_gcn<<<dim3(4, 4, 32), 256, 0, stream>>>(ADJh, ADJl, STh, STl, gc_b,
                                            bn1_g, bn1_b, bn1_m, bn1_v, Gh, Gl);
  k_hh<<<dim3(4, 128), 256, 0, stream>>>(Gh, Gl, GAh, GAl, HHh, HHl);
  k_vt<<<512, 256, 0, stream>>>(HHh, HHT);
  k_attn<<<1024, 256, 0, stream>>>(HHh, HHl, HHT, OP);
  k_conv_mfma<<<dim3(4, 128), 256, 0, stream>>>(OP, WT, conv_b,
                                                bn2_g, bn2_b, bn2_m, bn2_v, out);
}

// Round 7
// 293.468 us; speedup vs baseline: 1.0214x; 1.0214x over previous
//
#include <hip/hip_runtime.h>
#include <math.h>

// Problem constants (B,N,F_IN,HID,OUT,H,D) = (32,512,256,512,512,4,128)
#define BATCH 32
#define NNODE 512
#define FIN   256
#define HIDC  512
#define OUTC  512
#define NHEAD 4
#define HDIM  128
#define EPSV  1e-5f
#define ALPHA_LR 0.2f

typedef _Float16 half8 __attribute__((ext_vector_type(8)));
typedef _Float16 half4v __attribute__((ext_vector_type(4)));
typedef float floatx4 __attribute__((ext_vector_type(4)));

#define GLOBAL_TO_LDS16(g, l)                                                  \
  __builtin_amdgcn_global_load_lds(                                            \
      (const __attribute__((address_space(1))) void*)(g),                      \
      (__attribute__((address_space(3))) void*)(l), 16, 0, 0)

// ---------------------------------------------------------------------------
// Generic 128x128 split-fp16 MFMA GEMM core (unchanged).
// ---------------------------------------------------------------------------
__device__ __forceinline__ void split_gemm_acc(
    const _Float16* __restrict__ Ah, const _Float16* __restrict__ Al, int lda,
    const _Float16* __restrict__ Bh, const _Float16* __restrict__ Bl, int ldb,
    int K, int rowBase, int colBase,
    _Float16* sAh, _Float16* sAl, _Float16* sBh, _Float16* sBl,
    floatx4 acc[4][4], int tid) {
  const int lane = tid & 63, wave = tid >> 6;
  const int wr = (wave >> 1) * 64, wc = (wave & 1) * 64;
  const int fr = lane & 15, q = lane >> 4;
  const int r = tid >> 2, ko = (tid & 3) * 8;
  for (int k0 = 0; k0 < K; k0 += 32) {
    GLOBAL_TO_LDS16(&Ah[(size_t)(rowBase + r) * lda + k0 + ko], &sAh[tid * 8]);
    GLOBAL_TO_LDS16(&Ah[(size_t)(rowBase + r + 64) * lda + k0 + ko], &sAh[2048 + tid * 8]);
    GLOBAL_TO_LDS16(&Al[(size_t)(rowBase + r) * lda + k0 + ko], &sAl[tid * 8]);
    GLOBAL_TO_LDS16(&Al[(size_t)(rowBase + r + 64) * lda + k0 + ko], &sAl[2048 + tid * 8]);
    GLOBAL_TO_LDS16(&Bh[(size_t)(colBase + r) * ldb + k0 + ko], &sBh[tid * 8]);
    GLOBAL_TO_LDS16(&Bh[(size_t)(colBase + r + 64) * ldb + k0 + ko], &sBh[2048 + tid * 8]);
    GLOBAL_TO_LDS16(&Bl[(size_t)(colBase + r) * ldb + k0 + ko], &sBl[tid * 8]);
    GLOBAL_TO_LDS16(&Bl[(size_t)(colBase + r + 64) * ldb + k0 + ko], &sBl[2048 + tid * 8]);
    __syncthreads();
    half8 ah[4], al4[4], bh[4], bl4[4];
#pragma unroll
    for (int i = 0; i < 4; ++i) {
      ah[i]  = *(const half8*)&sAh[(wr + i * 16 + fr) * 32 + q * 8];
      al4[i] = *(const half8*)&sAl[(wr + i * 16 + fr) * 32 + q * 8];
    }
#pragma unroll
    for (int j = 0; j < 4; ++j) {
      bh[j]  = *(const half8*)&sBh[(wc + j * 16 + fr) * 32 + q * 8];
      bl4[j] = *(const half8*)&sBl[(wc + j * 16 + fr) * 32 + q * 8];
    }
#pragma unroll
    for (int i = 0; i < 4; ++i)
#pragma unroll
      for (int j = 0; j < 4; ++j) {
        acc[i][j] = __builtin_amdgcn_mfma_f32_16x16x32_f16(al4[i], bh[j], acc[i][j], 0, 0, 0);
        acc[i][j] = __builtin_amdgcn_mfma_f32_16x16x32_f16(ah[i], bl4[j], acc[i][j], 0, 0, 0);
        acc[i][j] = __builtin_amdgcn_mfma_f32_16x16x32_f16(ah[i], bh[j], acc[i][j], 0, 0, 0);
      }
    __syncthreads();
  }
}

// ---------------------------------------------------------------------------
// Prep: splits + conv weight transform + OP halo zero.
// ---------------------------------------------------------------------------
__global__ __launch_bounds__(256) void k_prep(
    const float* __restrict__ adj, const float* __restrict__ gcw,
    const float* __restrict__ gatw, const float* __restrict__ cw,
    _Float16* __restrict__ ADJh, _Float16* __restrict__ ADJl,
    _Float16* __restrict__ GWh, _Float16* __restrict__ GWl,
    _Float16* __restrict__ GAh, _Float16* __restrict__ GAl,
    _Float16* __restrict__ WT, _Float16* __restrict__ OP) {
  const int i = blockIdx.x * 256 + threadIdx.x;
  if (i < 262144) {
    float v = adj[i];
    _Float16 h = (_Float16)v;
    ADJh[i] = h; ADJl[i] = (_Float16)(v - (float)h);
  } else if (i < 393216) {
    int j = i - 262144;
    int n = j >> 8, k = j & 255;
    float v = gcw[(size_t)k * HIDC + n];
    _Float16 h = (_Float16)v;
    GWh[j] = h; GWl[j] = (_Float16)(v - (float)h);
  } else if (i < 655360) {
    int j = i - 393216;
    float v = gatw[j];
    _Float16 h = (_Float16)v;
    GAh[j] = h; GAl[j] = (_Float16)(v - (float)h);
  } else if (i < 1441792) {
    int j = i - 655360;
    int n = j / 1536, kk = j - n * 1536;
    int tap = kk >> 9, ci = kk & 511;
    WT[j] = (_Float16)cw[(size_t)n * 1536 + ci * 3 + tap];
  } else if (i < 1474560) {
    int j = i - 1441792;
    int b = j >> 10, rs = (j >> 9) & 1, c = j & 511;
    OP[((size_t)b * 514 + rs * 513) * OUTC + c] = (_Float16)0.f;
  }
}

// x [16384,256] fp32 -> hi/lo fp16
__global__ __launch_bounds__(256) void k_xsplit(const float* __restrict__ X,
                                                _Float16* __restrict__ Xh,
                                                _Float16* __restrict__ Xl) {
  const int i = (blockIdx.x * 256 + threadIdx.x) * 4;
  float4 v = *(const float4*)&X[i];
  half4v h, l;
  h[0] = (_Float16)v.x; l[0] = (_Float16)(v.x - (float)h[0]);
  h[1] = (_Float16)v.y; l[1] = (_Float16)(v.y - (float)h[1]);
  h[2] = (_Float16)v.z; l[2] = (_Float16)(v.z - (float)h[2]);
  h[3] = (_Float16)v.w; l[3] = (_Float16)(v.w - (float)h[3]);
  *(half4v*)&Xh[i] = h;
  *(half4v*)&Xl[i] = l;
}

// ---------------------------------------------------------------------------
// support^T = gc_w^T @ x^T : M=512(ch) N=16384(bn) K=256. Split output.
// ---------------------------------------------------------------------------
__global__ __launch_bounds__(256) void k_support_t(
    const _Float16* __restrict__ GWh, const _Float16* __restrict__ GWl,
    const _Float16* __restrict__ Xh, const _Float16* __restrict__ Xl,
    _Float16* __restrict__ STh, _Float16* __restrict__ STl) {
  __shared__ _Float16 sm[4][4096];
  const int tid = threadIdx.x;
  const int rowBase = blockIdx.y * 128, colBase = blockIdx.x * 128;
  floatx4 acc[4][4] = {};
  split_gemm_acc(GWh, GWl, FIN, Xh, Xl, FIN, FIN, rowBase, colBase,
                 sm[0], sm[1], sm[2], sm[3], acc, tid);
  const int lane = tid & 63, wave = tid >> 6;
  const int wr = (wave >> 1) * 64, wc = (wave & 1) * 64;
  const int fr = lane & 15, q = lane >> 4;
#pragma unroll
  for (int i = 0; i < 4; ++i) {
    const int ch0 = rowBase + wr + i * 16 + q * 4;
#pragma unroll
    for (int rg = 0; rg < 4; ++rg) {
      size_t base = (size_t)(ch0 + rg) * 16384 + colBase + wc + fr;
#pragma unroll
      for (int j = 0; j < 4; ++j) {
        float v = acc[i][j][rg];
        _Float16 h = (_Float16)v;
        STh[base + j * 16] = h;
        STl[base + j * 16] = (_Float16)(v - (float)h);
      }
    }
  }
}

// ---------------------------------------------------------------------------
// g = relu(bn1(adj @ support_b + gc_b)) per batch. Split output.
// ---------------------------------------------------------------------------
__global__ __launch_bounds__(256) void k_gcn(
    const _Float16* __restrict__ ADJh, const _Float16* __restrict__ ADJl,
    const _Float16* __restrict__ STh, const _Float16* __restrict__ STl,
    const float* __restrict__ gcb, const float* __restrict__ g1,
    const float* __restrict__ b1, const float* __restrict__ m1,
    const float* __restrict__ v1,
    _Float16* __restrict__ Gh, _Float16* __restrict__ Gl) {
  __shared__ _Float16 sm[4][4096];
  const int tid = threadIdx.x;
  const int rowBase = blockIdx.y * 128, colBase = blockIdx.x * 128;
  const int b = blockIdx.z;
  floatx4 acc[4][4] = {};
  split_gemm_acc(ADJh, ADJl, NNODE, STh + (size_t)b * NNODE, STl + (size_t)b * NNODE,
                 16384, NNODE, rowBase, colBase, sm[0], sm[1], sm[2], sm[3], acc, tid);
  const int lane = tid & 63, wave = tid >> 6;
  const int wr = (wave >> 1) * 64, wc = (wave & 1) * 64;
  const int fr = lane & 15, q = lane >> 4;
  float sc[4], of[4];
#pragma unroll
  for (int j = 0; j < 4; ++j) {
    int c = colBase + wc + j * 16 + fr;
    float s = g1[c] * rsqrtf(v1[c] + EPSV);
    sc[j] = s;
    of[j] = (gcb[c] - m1[c]) * s + b1[c];
  }
#pragma unroll
  for (int i = 0; i < 4; ++i) {
    const int n0 = rowBase + wr + i * 16 + q * 4;
#pragma unroll
    for (int rg = 0; rg < 4; ++rg) {
      size_t base = ((size_t)b * NNODE + n0 + rg) * HIDC + colBase + wc + fr;
#pragma unroll
      for (int j = 0; j < 4; ++j) {
        float v = fmaxf(fmaf(acc[i][j][rg], sc[j], of[j]), 0.0f);
        _Float16 h = (_Float16)v;
        Gh[base + j * 16] = h;
        Gl[base + j * 16] = (_Float16)(v - (float)h);
      }
    }
  }
}

// ---------------------------------------------------------------------------
// hh = g @ gat_w^T : M=16384 N=512 K=512. Split output.
// ---------------------------------------------------------------------------
__global__ __launch_bounds__(256) void k_hh(
    const _Float16* __restrict__ Gh, const _Float16* __restrict__ Gl,
    const _Float16* __restrict__ GAh, const _Float16* __restrict__ GAl,
    _Float16* __restrict__ HHh, _Float16* __restrict__ HHl) {
  __shared__ _Float16 sm[4][4096];
  const int tid = threadIdx.x;
  const int rowBase = blockIdx.y * 128, colBase = blockIdx.x * 128;
  floatx4 acc[4][4] = {};
  split_gemm_acc(Gh, Gl, HIDC, GAh, GAl, HIDC, HIDC, rowBase, colBase,
                 sm[0], sm[1], sm[2], sm[3], acc, tid);
  const int lane = tid & 63, wave = tid >> 6;
  const int wr = (wave >> 1) * 64, wc = (wave & 1) * 64;
  const int fr = lane & 15, q = lane >> 4;
#pragma unroll
  for (int i = 0; i < 4; ++i) {
    const int r0 = rowBase + wr + i * 16 + q * 4;
#pragma unroll
    for (int rg = 0; rg < 4; ++rg) {
      size_t base = (size_t)(r0 + rg) * OUTC + colBase + wc + fr;
#pragma unroll
      for (int j = 0; j < 4; ++j) {
        float v = acc[i][j][rg];
        _Float16 h = (_Float16)v;
        HHh[base + j * 16] = h;
        HHl[base + j * 16] = (_Float16)(v - (float)h);
      }
    }
  }
}

// ---------------------------------------------------------------------------
// k_vt: HHT[(bb*4+h)*128 + d][node] = HHh[bb*512+node][h*128+d]
// ---------------------------------------------------------------------------
__global__ __launch_bounds__(256) void k_vt(const _Float16* __restrict__ HHh,
                                            _Float16* __restrict__ HHT) {
  __shared__ _Float16 sT[128 * 132];
  const int bt = blockIdx.x;           // 0..511
  const int nt = bt & 3, g = bt >> 2;  // g = bb*4+h
  const int bb = g >> 2, h = g & 3;
  const int tid = threadIdx.x;
  const int rr = tid >> 4, cc = (tid & 15) * 8;
#pragma unroll
  for (int it = 0; it < 8; ++it) {
    int node = rr + it * 16;
    half8 v = *(const half8*)&HHh[((size_t)bb * 512 + nt * 128 + node) * 512 + h * 128 + cc];
#pragma unroll
    for (int e = 0; e < 8; ++e) sT[(cc + e) * 132 + node] = v[e];
  }
  __syncthreads();
#pragma unroll
  for (int it = 0; it < 8; ++it) {
    int d = rr + it * 16;
    half8 v;
#pragma unroll
    for (int e = 0; e < 8; ++e) v[e] = sT[d * 132 + cc + e];
    *(half8*)&HHT[((size_t)g * 128 + d) * 512 + nt * 128 + cc] = v;
  }
}

// ---------------------------------------------------------------------------
// Fused flash attention, restructured: 4 barriers/kt, fat MFMA bursts.
// 64 q-rows/block, grid 1024, XCD-grouped. LDS 40.5 KB -> 3 blocks/CU.
// ---------------------------------------------------------------------------
__global__ __launch_bounds__(256, 3) void k_attn(
    const _Float16* __restrict__ HHh, const _Float16* __restrict__ HHl,
    const _Float16* __restrict__ HHT, _Float16* __restrict__ OP) {
  __shared__ _Float16 sK[8][2048];   // tiles 0-3: K hi (k0=0..3), 4-7: K lo
  __shared__ _Float16 sP[64 * 68];   // [qrow][64 keys] stride 68
  _Float16* sV = &sK[0][0];          // V overlays dead K region after QK burst
  const int tid = threadIdx.x;
  const int lane = tid & 63, wave = tid >> 6;
  const int fr = lane & 15, q = lane >> 4;
  const int id = blockIdx.x;
  const int slot = id >> 3;
  const int g = (id & 7) + 8 * (slot >> 3);   // 0..127, all q-slots same id%8
  const int qBase = (slot & 7) * 64;
  const int bb = g >> 2, h = g & 3;
  const int w16 = wave * 16;
  const _Float16* Qh = HHh + (size_t)bb * NNODE * OUTC + h * HDIM;
  const _Float16* Ql = HHl + (size_t)bb * NNODE * OUTC + h * HDIM;
  const _Float16* VT = HHT + (size_t)g * HDIM * NNODE;  // [128 d][512 nodes]
  const int rk = tid >> 2, ck = (tid & 3) * 8;

  // Q fragments in registers (A layout: m=fr, k=k0*32+q*8+j), loaded once.
  half8 qh[4], ql[4];
#pragma unroll
  for (int k0 = 0; k0 < 4; ++k0) {
    const size_t off = (size_t)(qBase + w16 + fr) * OUTC + k0 * 32 + q * 8;
    qh[k0] = *(const half8*)&Qh[off];
    ql[k0] = *(const half8*)&Ql[off];
  }

  floatx4 oacc[8] = {};
  float m_i[4], l_i[4];
#pragma unroll
  for (int rg = 0; rg < 4; ++rg) { m_i[rg] = -1e30f; l_i[rg] = 0.f; }

  for (int kt = 0; kt < 8; ++kt) {
    const int ktb = kt * 64;
    // ---- stage whole 64-key K-tile (hi+lo, 32 KB, 8 sub-tiles) ----
#pragma unroll
    for (int t = 0; t < 4; ++t) {
      GLOBAL_TO_LDS16(&Qh[(size_t)(ktb + rk) * OUTC + t * 32 + ck], &sK[t][tid * 8]);
      GLOBAL_TO_LDS16(&Ql[(size_t)(ktb + rk) * OUTC + t * 32 + ck], &sK[4 + t][tid * 8]);
    }
    __syncthreads();
    // ---- S = Q @ K^T: one 48-MFMA burst ----
    floatx4 sacc[4] = {};
#pragma unroll
    for (int k0 = 0; k0 < 4; ++k0)
#pragma unroll
      for (int j = 0; j < 4; ++j) {
        half8 bh = *(const half8*)&sK[k0][(j * 16 + fr) * 32 + q * 8];
        half8 bl = *(const half8*)&sK[4 + k0][(j * 16 + fr) * 32 + q * 8];
        sacc[j] = __builtin_amdgcn_mfma_f32_16x16x32_f16(ql[k0], bh, sacc[j], 0, 0, 0);
        sacc[j] = __builtin_amdgcn_mfma_f32_16x16x32_f16(qh[k0], bl, sacc[j], 0, 0, 0);
        sacc[j] = __builtin_amdgcn_mfma_f32_16x16x32_f16(qh[k0], bh, sacc[j], 0, 0, 0);
      }
    __syncthreads();   // sK fully consumed; safe to overlay with V
    // ---- LeakyReLU + online softmax ----
#pragma unroll
    for (int j = 0; j < 4; ++j)
#pragma unroll
      for (int rg = 0; rg < 4; ++rg) {
        float v = sacc[j][rg];
        sacc[j][rg] = v > 0.f ? v : ALPHA_LR * v;
      }
#pragma unroll
    for (int rg = 0; rg < 4; ++rg) {
      float mx = sacc[0][rg];
#pragma unroll
      for (int j = 1; j < 4; ++j) mx = fmaxf(mx, sacc[j][rg]);
      mx = fmaxf(mx, __shfl_xor(mx, 1));
      mx = fmaxf(mx, __shfl_xor(mx, 2));
      mx = fmaxf(mx, __shfl_xor(mx, 4));
      mx = fmaxf(mx, __shfl_xor(mx, 8));
      float mnew = fmaxf(m_i[rg], mx);
      float alpha = __expf(m_i[rg] - mnew);
      m_i[rg] = mnew;
      float sum = 0.f;
#pragma unroll
      for (int j = 0; j < 4; ++j) {
        float p = __expf(sacc[j][rg] - mnew);
        sacc[j][rg] = p;
        sum += p;
      }
      sum += __shfl_xor(sum, 1);
      sum += __shfl_xor(sum, 2);
      sum += __shfl_xor(sum, 4);
      sum += __shfl_xor(sum, 8);
      l_i[rg] = l_i[rg] * alpha + sum;
#pragma unroll
      for (int j = 0; j < 8; ++j) oacc[j][rg] *= alpha;   // ALL 8 d-cols
    }
    // ---- stage V (2 ks-tiles from HHT, overlays sK) + write P ----
#pragma unroll
    for (int l = 0; l < 4; ++l)
      GLOBAL_TO_LDS16(&VT[(size_t)((l >> 1) * 64 + rk) * NNODE + ktb + (l & 1) * 32 + ck],
                      &sV[(l & 1) * 4096 + (l >> 1) * 2048 + tid * 8]);
#pragma unroll
    for (int j = 0; j < 4; ++j)
#pragma unroll
      for (int rg = 0; rg < 4; ++rg)
        sP[(w16 + q * 4 + rg) * 68 + j * 16 + fr] = (_Float16)sacc[j][rg];
    __syncthreads();
    // ---- O += P @ V: one 16-MFMA burst ----
#pragma unroll
    for (int ks = 0; ks < 2; ++ks) {
      half8 pa = *(const half8*)&sP[(w16 + fr) * 68 + ks * 32 + q * 8];
#pragma unroll
      for (int j = 0; j < 8; ++j) {
        half8 bv = *(const half8*)&sV[ks * 4096 + (j * 16 + fr) * 32 + q * 8];
        oacc[j] = __builtin_amdgcn_mfma_f32_16x16x32_f16(pa, bv, oacc[j], 0, 0, 0);
      }
    }
    __syncthreads();   // sV dead before next kt's K staging
  }
  // ---- normalize + write into padded conv input ----
#pragma unroll
  for (int rg = 0; rg < 4; ++rg) {
    const float inv = 1.0f / l_i[rg];
    const int node = qBase + w16 + q * 4 + rg;
    size_t base = ((size_t)bb * 514 + 1 + node) * OUTC + h * HDIM + fr;
#pragma unroll
    for (int j = 0; j < 8; ++j)
      OP[base + j * 16] = (_Float16)(oacc[j][rg] * inv);
  }
}

// ---------------------------------------------------------------------------
// y = relu(bn2(conv1d(o)+conv_b)) via fp16 MFMA GEMM, XCD-swizzled.
// ---------------------------------------------------------------------------
__global__ __launch_bounds__(256) void k_conv_mfma(
    const _Float16* __restrict__ OP, const _Float16* __restrict__ WT,
    const float* __restrict__ cb, const float* __restrict__ g2,
    const float* __restrict__ b2, const float* __restrict__ m2,
    const float* __restrict__ v2, float* __restrict__ Y) {
  __shared__ _Float16 At[128 * 32];
  __shared__ _Float16 Bt[128 * 32];
  const int tid = threadIdx.x;
  const int lane = tid & 63, wave = tid >> 6;
  const int wr = (wave >> 1) * 64, wc = (wave & 1) * 64;
  const int id = blockIdx.y * 4 + blockIdx.x;
  const int jj = id >> 3;
  const int rowBase = ((id & 7) * 16 + (jj >> 2)) * 128;
  const int colBase = (jj & 3) * 128;
  const int b = rowBase >> 9;
  const int n0 = rowBase & 511;
  const int r = tid >> 2;
  const int ko = (tid & 3) * 8;
  floatx4 acc[4][4] = {};
  for (int k0 = 0; k0 < 3 * OUTC; k0 += 32) {
    const int tap = k0 >> 9;
    const int cib = k0 & 511;
    const size_t abase = ((size_t)b * 514 + n0 + tap) * OUTC + cib + ko;
    GLOBAL_TO_LDS16(&OP[abase + (size_t)r * OUTC],        &At[tid * 8]);
    GLOBAL_TO_LDS16(&OP[abase + (size_t)(r + 64) * OUTC], &At[2048 + tid * 8]);
    GLOBAL_TO_LDS16(&WT[(size_t)(colBase + r) * 1536 + k0 + ko],      &Bt[tid * 8]);
    GLOBAL_TO_LDS16(&WT[(size_t)(colBase + r + 64) * 1536 + k0 + ko], &Bt[2048 + tid * 8]);
    __syncthreads();
    const int fr = lane & 15, q = lane >> 4;
    half8 af[4], bf[4];
#pragma unroll
    for (int i = 0; i < 4; ++i)
      af[i] = *(const half8*)&At[(wr + i * 16 + fr) * 32 + q * 8];
#pragma unroll
    for (int j = 0; j < 4; ++j)
      bf[j] = *(const half8*)&Bt[(wc + j * 16 + fr) * 32 + q * 8];
#pragma unroll
    for (int i = 0; i < 4; ++i)
#pragma unroll
      for (int j = 0; j < 4; ++j)
        acc[i][j] = __builtin_amdgcn_mfma_f32_16x16x32_f16(af[i], bf[j], acc[i][j], 0, 0, 0);
    __syncthreads();
  }
  const int fr = lane & 15, q = lane >> 4;
  float sc[4], of[4];
#pragma unroll
  for (int j = 0; j < 4; ++j) {
    int c = colBase + wc + j * 16 + fr;
    float s = g2[c] * rsqrtf(v2[c] + EPSV);
    sc[j] = s;
    of[j] = (cb[c] - m2[c]) * s + b2[c];
  }
#pragma unroll
  for (int i = 0; i < 4; ++i) {
    const int R0r = rowBase + wr + i * 16 + q * 4;
#pragma unroll
    for (int rg = 0; rg < 4; ++rg) {
      float* dst = &Y[(size_t)(R0r + rg) * OUTC + colBase + wc + fr];
#pragma unroll
      for (int j = 0; j < 4; ++j)
        dst[j * 16] = fmaxf(fmaf(acc[i][j][rg], sc[j], of[j]), 0.0f);
    }
  }
}

// ---------------------------------------------------------------------------
extern "C" void kernel_launch(void* const* d_in, const int* in_sizes, int n_in,
                              void* d_out, int out_size, void* d_ws, size_t ws_size,
                              hipStream_t stream) {
  const float* x     = (const float*)d_in[0];
  const float* adj   = (const float*)d_in[1];
  const float* gc_w  = (const float*)d_in[2];
  const float* gc_b  = (const float*)d_in[3];
  const float* bn1_g = (const float*)d_in[4];
  const float* bn1_b = (const float*)d_in[5];
  const float* bn1_m = (const float*)d_in[6];
  const float* bn1_v = (const float*)d_in[7];
  const float* gat_w = (const float*)d_in[8];
  const float* conv_w= (const float*)d_in[9];
  const float* conv_b= (const float*)d_in[10];
  const float* bn2_g = (const float*)d_in[11];
  const float* bn2_b = (const float*)d_in[12];
  const float* bn2_m = (const float*)d_in[13];
  const float* bn2_v = (const float*)d_in[14];
  float* out = (float*)d_out;

  char* ws = (char*)d_ws;
  _Float16* STh = (_Float16*)(ws + 0);
  _Float16* STl = (_Float16*)(ws + 16777216);
  _Float16* HHh = (_Float16*)(ws + 0);
  _Float16* HHl = (_Float16*)(ws + 16777216);
  _Float16* Xh  = (_Float16*)(ws + 33554432);
  _Float16* Xl  = (_Float16*)(ws + 41943040);
  _Float16* Gh  = (_Float16*)(ws + 33554432);
  _Float16* Gl  = (_Float16*)(ws + 50331648);
  _Float16* HHT = (_Float16*)(ws + 33554432);
  _Float16* OP  = (_Float16*)(ws + 67108864);
  _Float16* WT  = (_Float16*)(ws + 83951616);
  _Float16* ADJh= (_Float16*)(ws + 85524480);
  _Float16* ADJl= (_Float16*)(ws + 86048768);
  _Float16* GWh = (_Float16*)(ws + 86573056);
  _Float16* GWl = (_Float16*)(ws + 86835200);
  _Float16* GAh = (_Float16*)(ws + 87097344);
  _Float16* GAl = (_Float16*)(ws + 87621632);

  k_prep<<<5760, 256, 0, stream>>>(adj, gc_w, gat_w, conv_w,
                                   ADJh, ADJl, GWh, GWl, GAh, GAl, WT, OP);
  k_xsplit<<<4096, 256, 0, stream>>>(x, Xh, Xl);
  k_support_t<<<dim3(128, 4), 256, 0, stream>>>(GWh, GWl, Xh, Xl, STh, STl);
  k_gcn<<<dim3(4, 4, 32), 256, 0, stream>>>(ADJh, ADJl, STh, STl, gc_b,
                                            bn1_g, bn1_b, bn1_m, bn1_v, Gh, Gl);
  k_hh<<<dim3(4, 128), 256, 0, stream>>>(Gh, Gl, GAh, GAl, HHh, HHl);
  k_vt<<<512, 256, 0, stream>>>(HHh, HHT);
  k_attn<<<1024, 256, 0, stream>>>(HHh, HHl, HHT, OP);
  k_conv_mfma<<<dim3(4, 128), 256, 0, stream>>>(OP, WT, conv_b,
                                                bn2_g, bn2_b, bn2_m, bn2_v, out);
}